// Round 19
// baseline (224.852 us; speedup 1.0000x reference)
//
#include <hip/hip_runtime.h>
#include <stdint.h>

#define Hdim 112
#define Wdim 112
#define CIN  128
#define COUT 128
#define NB   32
#define HW   (Hdim*Wdim)   // 12544
#define HALO_W 66
#define HALO_PX (4*HALO_W)          // 264 pixels (4 rows x 66 cols)
#define SSTR (HALO_PX*16)           // 4224 B per ci-16 slot

// ws layout:
//   Wi8 : int8 [9][COUT][CIN]  @ 0        (147456 B)  weight signs as +-1
//   pkx : uint4[NB*HW]         @ 147456   (6.4 MB)    packed activation sign bits

typedef int   v4i __attribute__((ext_vector_type(4)));
typedef int  v16i __attribute__((ext_vector_type(16)));
typedef float v4f __attribute__((ext_vector_type(4)));

__global__ void pack_w_i8(const float* __restrict__ W, char* __restrict__ Wi8) {
    int t = blockIdx.x * blockDim.x + threadIdx.x;
    if (t >= COUT * 9) return;
    int co = t / 9, tap = t % 9;
    const float* wp = W + (size_t)co * CIN * 9 + tap;
    uint32_t* dst = (uint32_t*)(Wi8 + ((size_t)tap * COUT + co) * CIN);
    #pragma unroll
    for (int c4 = 0; c4 < 32; c4++) {
        uint32_t word = 0;
        #pragma unroll
        for (int j = 0; j < 4; j++) {
            uint32_t neg = __float_as_uint(wp[(size_t)(c4 * 4 + j) * 9]) >> 31;
            word |= (neg ? 0xFFu : 0x01u) << (8 * j);
        }
        dst[c4] = word;
    }
}

// each thread packs 4 consecutive pixels across all 128 channels.
// x is 205 MB single-use -> nontemporal loads keep it out of L2/L3.
__global__ __launch_bounds__(256) void pack_x_kernel(const float* __restrict__ x,
                                                     uint4* __restrict__ pkx) {
    int gid = blockIdx.x * blockDim.x + threadIdx.x;   // 0..100351
    int n = gid / (HW / 4);
    int p = (gid - n * (HW / 4)) * 4;
    const float* xp = x + (size_t)n * CIN * HW + p;
    uint32_t m[4][4] = {{0,0,0,0},{0,0,0,0},{0,0,0,0},{0,0,0,0}};
    #pragma unroll
    for (int c = 0; c < CIN; c++) {
        v4f v = __builtin_nontemporal_load(
            reinterpret_cast<const v4f*>(xp + (size_t)c * HW));
        int q = c >> 5, s = c & 31;
        m[0][q] |= (__float_as_uint(v.x) >> 31) << s;
        m[1][q] |= (__float_as_uint(v.y) >> 31) << s;
        m[2][q] |= (__float_as_uint(v.z) >> 31) << s;
        m[3][q] |= (__float_as_uint(v.w) >> 31) << s;
    }
    uint4* op = pkx + (size_t)n * HW + p;
    #pragma unroll
    for (int j = 0; j < 4; j++)
        op[j] = make_uint4(m[j][0], m[j][1], m[j][2], m[j][3]);
}

// spread low 4 bits into 4 bytes: bit=0 -> 0x01 (+1), bit=1 -> 0xFF (-1)
__device__ __forceinline__ uint32_t expand4(uint32_t b) {
    uint32_t s = ((b & 0xFu) * 0x00204081u) & 0x01010101u;
    return 0x01010101u ^ (s * 0xFEu);
}

// implicit-GEMM binconv via i8 MFMA — ALL-TAP WEIGHTS RESIDENT (sized to fit).
// Lesson R9/R10/R15/R16/R18: per-tap global A-loads inside the K-loop cannot
// be scheduled as prefetch from HIP source (issue gets sunk even with asm
// completion anchors). So the loads leave the loop entirely:
//   wave = 32co x 64px -> acc 2xv16i = 32 AGPR; Wreg[9][4] = 144; ~210 total
//   <= 256-reg budget at (256,2) -> fits WITHOUT allocator cuts (R10 died at
//   272 > 256). One-time asm "+v" anchor on all 36 weight regs outside the
//   loop makes remat impossible (SSA: later uses read anchor outputs).
// Inner loop: pure ds_read_b128 + MFMA. Zero global ops, zero vmcnt waits.
// Block = 4 waves = 64co x (2 rows x 64 cols); halo 4x66 i8 [slot][px][16B]
// conflict-free; col chunks 0/48, chunk 1 skips local cols <16 on store.
// OOB masked after expand -> exact zero padding. NT stores.
__global__ __launch_bounds__(256, 2) void binconv_mfma(
    const uint4* __restrict__ pkx, const char* __restrict__ Wi8,
    const float* __restrict__ bias, float* __restrict__ out) {
    __shared__ uint4 halo4[8 * HALO_PX];    // 33792 B
    char* halo = (char*)halo4;

    int tid = threadIdx.x;
    int c0 = blockIdx.x ? 48 : 0;           // col-chunk origin
    int h0 = blockIdx.y * 2;
    int bz = blockIdx.z;
    int n  = bz >> 1;
    int cohalf = (bz & 1) * 64;

    // stage 4x66 halo: expand 128 sign bits -> 128 i8 (+-1, 0 if OOB)
    for (int i = tid; i < HALO_PX; i += 256) {
        int r = i / HALO_W, c = i - r * HALO_W;
        int h = h0 - 1 + r, w = c0 - 1 + c;
        bool valid = (h >= 0) && (h < Hdim) && (w >= 0) && (w < Wdim);
        uint32_t keep = valid ? 0xFFFFFFFFu : 0u;
        int hc = min(max(h, 0), Hdim - 1);
        int wc = min(max(w, 0), Wdim - 1);
        uint4 bits = pkx[(size_t)n * HW + hc * Wdim + wc];
        uint32_t src[4] = {bits.x, bits.y, bits.z, bits.w};
        #pragma unroll
        for (int s = 0; s < 8; s++) {       // slot s = ci 16s..16s+15
            uint32_t q = src[s >> 1] >> ((s & 1) * 16);
            uint4 ov;
            ov.x = expand4(q)       & keep;
            ov.y = expand4(q >> 4)  & keep;
            ov.z = expand4(q >> 8)  & keep;
            ov.w = expand4(q >> 12) & keep;
            *reinterpret_cast<uint4*>(&halo[s * SSTR + i * 16]) = ov;
        }
    }

    int wid = tid >> 6, l = tid & 63;
    int al = l & 31, ah = l >> 5;
    int cobase = cohalf + (wid & 1) * 32;   // wave's 32-co slice
    int ptb    = (wid >> 1) * 2;            // wave's px half (2 pt of 32)

    // halo byte base at tap (0,0) for the wave's two px tiles
    int hb[2];
    #pragma unroll
    for (int pt = 0; pt < 2; pt++) {
        int P = (ptb + pt) * 32 + al;       // linear px in 2x64 tile
        int r = P >> 6, c = P & 63;
        hb[pt] = (r * HALO_W + c) * 16 + ah * SSTR;
    }

    // ---- prologue: full 9-tap weight panel for this wave's 32 co ----
    const char* wA = Wi8 + ((size_t)cobase + al) * CIN + ah * 16;
    v4i Wreg[9][4];
    #pragma unroll
    for (int tap = 0; tap < 9; tap++)
        #pragma unroll
        for (int kk = 0; kk < 4; kk++)
            Wreg[tap][kk] = *reinterpret_cast<const v4i*>(
                wA + (size_t)tap * COUT * CIN + kk * 32);
    // SSA anchor: all 36 values must be materialized here, once; every use
    // below reads the anchor's outputs -> no remat/sink possible.
    asm volatile("" :
        "+v"(Wreg[0][0]), "+v"(Wreg[0][1]), "+v"(Wreg[0][2]), "+v"(Wreg[0][3]),
        "+v"(Wreg[1][0]), "+v"(Wreg[1][1]), "+v"(Wreg[1][2]), "+v"(Wreg[1][3]),
        "+v"(Wreg[2][0]), "+v"(Wreg[2][1]), "+v"(Wreg[2][2]), "+v"(Wreg[2][3]),
        "+v"(Wreg[3][0]), "+v"(Wreg[3][1]), "+v"(Wreg[3][2]), "+v"(Wreg[3][3]),
        "+v"(Wreg[4][0]), "+v"(Wreg[4][1]), "+v"(Wreg[4][2]), "+v"(Wreg[4][3]),
        "+v"(Wreg[5][0]), "+v"(Wreg[5][1]), "+v"(Wreg[5][2]), "+v"(Wreg[5][3]),
        "+v"(Wreg[6][0]), "+v"(Wreg[6][1]), "+v"(Wreg[6][2]), "+v"(Wreg[6][3]),
        "+v"(Wreg[7][0]), "+v"(Wreg[7][1]), "+v"(Wreg[7][2]), "+v"(Wreg[7][3]),
        "+v"(Wreg[8][0]), "+v"(Wreg[8][1]), "+v"(Wreg[8][2]), "+v"(Wreg[8][3]));

    v16i acc[2];
    #pragma unroll
    for (int pt = 0; pt < 2; pt++)
        #pragma unroll
        for (int i = 0; i < 16; i++) acc[pt][i] = 0;

    __syncthreads();

    #pragma unroll
    for (int tap = 0; tap < 9; tap++) {
        const int doff = ((tap / 3) * HALO_W + (tap % 3)) * 16;
        #pragma unroll
        for (int kk = 0; kk < 4; kk++) {
            int sb = kk * 2 * SSTR + doff;
            v4i b0 = *reinterpret_cast<const v4i*>(&halo[sb + hb[0]]);
            v4i b1 = *reinterpret_cast<const v4i*>(&halo[sb + hb[1]]);
            acc[0] = __builtin_amdgcn_mfma_i32_32x32x32_i8(Wreg[tap][kk], b0, acc[0], 0, 0, 0);
            acc[1] = __builtin_amdgcn_mfma_i32_32x32x32_i8(Wreg[tap][kk], b1, acc[1], 0, 0, 0);
        }
    }

    // epilogue: C col=lane&31 (pixel), row=(reg&3)+8*(reg>>2)+4*ah (co).
    // chunk 1 (c0=48) skips local cols <16 (already written by chunk 0).
    float* ob = out + (size_t)n * COUT * HW;
    #pragma unroll
    for (int reg = 0; reg < 16; reg++) {
        int co = cobase + (reg & 3) + ((reg >> 2) << 3) + (ah << 2);
        float bv = bias[co];
        #pragma unroll
        for (int pt = 0; pt < 2; pt++) {
            int P = (ptb + pt) * 32 + al;
            int cl = P & 63;
            if (c0 == 0 || cl >= 16) {
                size_t off = (size_t)co * HW + (size_t)(h0 + (P >> 6)) * Wdim + c0 + cl;
                __builtin_nontemporal_store((float)acc[pt][reg] + bv, &ob[off]);
            }
        }
    }
}

extern "C" void kernel_launch(void* const* d_in, const int* in_sizes, int n_in,
                              void* d_out, int out_size, void* d_ws, size_t ws_size,
                              hipStream_t stream) {
    const float* x = (const float*)d_in[0];
    const float* W = (const float*)d_in[1];
    const float* b = (const float*)d_in[2];
    float* out = (float*)d_out;
    char* ws = (char*)d_ws;
    char*  Wi8 = ws;
    uint4* pkx = (uint4*)(ws + 147456);

    pack_w_i8<<<dim3((COUT * 9 + 255) / 256), dim3(256), 0, stream>>>(W, Wi8);
    pack_x_kernel<<<dim3(NB * HW / 4 / 256), dim3(256), 0, stream>>>(x, pkx);
    binconv_mfma<<<dim3(2, Hdim / 2, NB * 2), dim3(256), 0, stream>>>(pkx, Wi8, b, out);
}

// Round 21
// 196.930 us; speedup vs baseline: 1.1418x; 1.1418x over previous
//
#include <hip/hip_runtime.h>
#include <stdint.h>

#define Hdim 112
#define Wdim 112
#define CIN  128
#define COUT 128
#define NB   32
#define HW   (Hdim*Wdim)   // 12544
#define HALO_W 66
#define HALO_PX (4*HALO_W)          // 264 pixels (4 rows x 66 cols)
#define SSTR (HALO_PX*16)           // 4224 B per ci-16 slot

// ws layout:
//   Wi8 : int8 [9][COUT][CIN]  @ 0        (147456 B)  weight signs as +-1
//   pkx : uint4[NB*HW]         @ 147456   (6.4 MB)    packed activation sign bits

typedef int   v4i __attribute__((ext_vector_type(4)));
typedef int  v16i __attribute__((ext_vector_type(16)));
typedef float v4f __attribute__((ext_vector_type(4)));

__global__ void pack_w_i8(const float* __restrict__ W, char* __restrict__ Wi8) {
    int t = blockIdx.x * blockDim.x + threadIdx.x;
    if (t >= COUT * 9) return;
    int co = t / 9, tap = t % 9;
    const float* wp = W + (size_t)co * CIN * 9 + tap;
    uint32_t* dst = (uint32_t*)(Wi8 + ((size_t)tap * COUT + co) * CIN);
    #pragma unroll
    for (int c4 = 0; c4 < 32; c4++) {
        uint32_t word = 0;
        #pragma unroll
        for (int j = 0; j < 4; j++) {
            uint32_t neg = __float_as_uint(wp[(size_t)(c4 * 4 + j) * 9]) >> 31;
            word |= (neg ? 0xFFu : 0x01u) << (8 * j);
        }
        dst[c4] = word;
    }
}

// each thread packs 4 consecutive pixels across all 128 channels.
// x is 205 MB single-use -> nontemporal loads keep it out of L2/L3.
__global__ __launch_bounds__(256) void pack_x_kernel(const float* __restrict__ x,
                                                     uint4* __restrict__ pkx) {
    int gid = blockIdx.x * blockDim.x + threadIdx.x;   // 0..100351
    int n = gid / (HW / 4);
    int p = (gid - n * (HW / 4)) * 4;
    const float* xp = x + (size_t)n * CIN * HW + p;
    uint32_t m[4][4] = {{0,0,0,0},{0,0,0,0},{0,0,0,0},{0,0,0,0}};
    #pragma unroll
    for (int c = 0; c < CIN; c++) {
        v4f v = __builtin_nontemporal_load(
            reinterpret_cast<const v4f*>(xp + (size_t)c * HW));
        int q = c >> 5, s = c & 31;
        m[0][q] |= (__float_as_uint(v.x) >> 31) << s;
        m[1][q] |= (__float_as_uint(v.y) >> 31) << s;
        m[2][q] |= (__float_as_uint(v.z) >> 31) << s;
        m[3][q] |= (__float_as_uint(v.w) >> 31) << s;
    }
    uint4* op = pkx + (size_t)n * HW + p;
    #pragma unroll
    for (int j = 0; j < 4; j++)
        op[j] = make_uint4(m[j][0], m[j][1], m[j][2], m[j][3]);
}

// spread low 4 bits into 4 bytes: bit=0 -> 0x01 (+1), bit=1 -> 0xFF (-1)
__device__ __forceinline__ uint32_t expand4(uint32_t b) {
    uint32_t s = ((b & 0xFu) * 0x00204081u) & 0x01010101u;
    return 0x01010101u ^ (s * 0xFEu);
}

// implicit-GEMM binconv via i8 MFMA — reuse_B=2 + ASM-ISSUE-PINNED prefetch.
// R20 postmortem: the multi-instruction load asm used "=v" outputs; without
// early-clobber the output tuple could alias the address pair (outputs are
// assumed written after inputs are read — false for load 1 of 4), so the
// address got clobbered -> wild load -> core dump. Fixed with "=&v".
// Schedule (guide T3/T4, rule #18): issue next tap's 8 A-loads via volatile
// asm at tap top (cannot be sunk/de-registered), 16 MFMAs, then
// s_waitcnt vmcnt(0) + sched_barrier(0) so the drain lands after compute
// and next tap's MFMAs can't hoist above it. Ping-pong Ab[2][2][4].
// Block = 128co x (2 rows x 64 cols), 4 waves = 64co x 64px each; each
// ds_read_b128 feeds 2 MFMAs. Col chunks 0-63 / 48-111 (chunk 1 skips
// local cols <16 on store). OOB masked after expand -> exact zero padding.
__global__ __launch_bounds__(256, 2) void binconv_mfma(
    const uint4* __restrict__ pkx, const char* __restrict__ Wi8,
    const float* __restrict__ bias, float* __restrict__ out) {
    __shared__ uint4 halo4[8 * HALO_PX];    // 33792 B
    char* halo = (char*)halo4;

    int tid = threadIdx.x;
    int c0 = blockIdx.x ? 48 : 0;           // col-chunk origin
    int h0 = blockIdx.y * 2;
    int n  = blockIdx.z;

    // stage 4x66 halo: expand 128 sign bits -> 128 i8 (+-1, 0 if OOB)
    for (int i = tid; i < HALO_PX; i += 256) {
        int r = i / HALO_W, c = i - r * HALO_W;
        int h = h0 - 1 + r, w = c0 - 1 + c;
        bool valid = (h >= 0) && (h < Hdim) && (w >= 0) && (w < Wdim);
        uint32_t keep = valid ? 0xFFFFFFFFu : 0u;
        int hc = min(max(h, 0), Hdim - 1);
        int wc = min(max(w, 0), Wdim - 1);
        uint4 bits = pkx[(size_t)n * HW + hc * Wdim + wc];
        uint32_t src[4] = {bits.x, bits.y, bits.z, bits.w};
        #pragma unroll
        for (int s = 0; s < 8; s++) {       // slot s = ci 16s..16s+15
            uint32_t q = src[s >> 1] >> ((s & 1) * 16);
            uint4 ov;
            ov.x = expand4(q)       & keep;
            ov.y = expand4(q >> 4)  & keep;
            ov.z = expand4(q >> 8)  & keep;
            ov.w = expand4(q >> 12) & keep;
            *reinterpret_cast<uint4*>(&halo[s * SSTR + i * 16]) = ov;
        }
    }

    int wid = tid >> 6, l = tid & 63;
    int al = l & 31, ah = l >> 5;
    int ctbase = (wid & 1) * 64;            // wave's co half (2 ct of 32)
    int ptb    = (wid >> 1) * 2;            // wave's px half (2 pt of 32)

    // halo byte base at tap (0,0) for the wave's two px tiles
    int hb[2];
    #pragma unroll
    for (int pt = 0; pt < 2; pt++) {
        int P = (ptb + pt) * 32 + al;       // linear px in 2x64 tile
        int r = P >> 6, c = P & 63;
        hb[pt] = (r * HALO_W + c) * 16 + ah * SSTR;
    }

    const char* wA = Wi8 + ((size_t)ctbase + al) * CIN + ah * 16;

    v16i acc[2][2];
    #pragma unroll
    for (int ct = 0; ct < 2; ct++)
        #pragma unroll
        for (int pt = 0; pt < 2; pt++)
            #pragma unroll
            for (int i = 0; i < 16; i++) acc[ct][pt][i] = 0;

    // ping-pong A fragments; tap 0 preloaded with plain loads
    v4i Ab[2][2][4];
    #pragma unroll
    for (int kk = 0; kk < 4; kk++) {
        Ab[0][0][kk] = *reinterpret_cast<const v4i*>(wA + kk * 32);
        Ab[0][1][kk] = *reinterpret_cast<const v4i*>(wA + 32 * CIN + kk * 32);
    }

    __syncthreads();

    #pragma unroll
    for (int tap = 0; tap < 9; tap++) {
        const int cur = tap & 1, nxt = cur ^ 1;
        if (tap < 8) {
            // issue next tap's 8 A-loads NOW (volatile asm: issue order pinned;
            // "=&v" early-clobber so outputs can't alias the address pair)
            const char* wt = wA + (size_t)(tap + 1) * COUT * CIN;
            uint64_t b0a = (uint64_t)wt;
            uint64_t b1a = (uint64_t)(wt + 32 * CIN);
            asm volatile(
                "global_load_dwordx4 %0, %4, off\n\t"
                "global_load_dwordx4 %1, %4, off offset:32\n\t"
                "global_load_dwordx4 %2, %4, off offset:64\n\t"
                "global_load_dwordx4 %3, %4, off offset:96"
                : "=&v"(Ab[nxt][0][0]), "=&v"(Ab[nxt][0][1]),
                  "=&v"(Ab[nxt][0][2]), "=&v"(Ab[nxt][0][3])
                : "v"(b0a));
            asm volatile(
                "global_load_dwordx4 %0, %4, off\n\t"
                "global_load_dwordx4 %1, %4, off offset:32\n\t"
                "global_load_dwordx4 %2, %4, off offset:64\n\t"
                "global_load_dwordx4 %3, %4, off offset:96"
                : "=&v"(Ab[nxt][1][0]), "=&v"(Ab[nxt][1][1]),
                  "=&v"(Ab[nxt][1][2]), "=&v"(Ab[nxt][1][3])
                : "v"(b1a));
            __builtin_amdgcn_sched_barrier(0);   // MFMAs may not move above the loads
        }
        const int doff = ((tap / 3) * HALO_W + (tap % 3)) * 16;
        #pragma unroll
        for (int kk = 0; kk < 4; kk++) {
            int sb = kk * 2 * SSTR + doff;
            v4i b0 = *reinterpret_cast<const v4i*>(&halo[sb + hb[0]]);
            v4i b1 = *reinterpret_cast<const v4i*>(&halo[sb + hb[1]]);
            acc[0][0] = __builtin_amdgcn_mfma_i32_32x32x32_i8(Ab[cur][0][kk], b0, acc[0][0], 0, 0, 0);
            acc[0][1] = __builtin_amdgcn_mfma_i32_32x32x32_i8(Ab[cur][0][kk], b1, acc[0][1], 0, 0, 0);
            acc[1][0] = __builtin_amdgcn_mfma_i32_32x32x32_i8(Ab[cur][1][kk], b0, acc[1][0], 0, 0, 0);
            acc[1][1] = __builtin_amdgcn_mfma_i32_32x32x32_i8(Ab[cur][1][kk], b1, acc[1][1], 0, 0, 0);
        }
        if (tap < 8) {
            // drain the prefetch AFTER this tap's compute; fence so next
            // tap's MFMAs (which read the asm outputs) can't hoist above.
            asm volatile("s_waitcnt vmcnt(0)" ::: "memory");
            __builtin_amdgcn_sched_barrier(0);
        }
    }

    // epilogue: C col=lane&31 (pixel), row=(reg&3)+8*(reg>>2)+4*ah (co).
    // chunk 1 (c0=48) skips local cols <16 (already written by chunk 0).
    float* ob = out + (size_t)n * COUT * HW;
    #pragma unroll
    for (int ct = 0; ct < 2; ct++) {
        #pragma unroll
        for (int reg = 0; reg < 16; reg++) {
            int co = ctbase + ct * 32 + (reg & 3) + ((reg >> 2) << 3) + (ah << 2);
            float bv = bias[co];
            #pragma unroll
            for (int pt = 0; pt < 2; pt++) {
                int P = (ptb + pt) * 32 + al;
                int cl = P & 63;
                if (c0 == 0 || cl >= 16) {
                    size_t off = (size_t)co * HW + (size_t)(h0 + (P >> 6)) * Wdim + c0 + cl;
                    __builtin_nontemporal_store((float)acc[ct][pt][reg] + bv, &ob[off]);
                }
            }
        }
    }
}

extern "C" void kernel_launch(void* const* d_in, const int* in_sizes, int n_in,
                              void* d_out, int out_size, void* d_ws, size_t ws_size,
                              hipStream_t stream) {
    const float* x = (const float*)d_in[0];
    const float* W = (const float*)d_in[1];
    const float* b = (const float*)d_in[2];
    float* out = (float*)d_out;
    char* ws = (char*)d_ws;
    char*  Wi8 = ws;
    uint4* pkx = (uint4*)(ws + 147456);

    pack_w_i8<<<dim3((COUT * 9 + 255) / 256), dim3(256), 0, stream>>>(W, Wi8);
    pack_x_kernel<<<dim3(NB * HW / 4 / 256), dim3(256), 0, stream>>>(x, pkx);
    binconv_mfma<<<dim3(2, Hdim / 2, NB), dim3(256), 0, stream>>>(pkx, Wi8, b, out);
}

// Round 22
// 124.176 us; speedup vs baseline: 1.8107x; 1.5859x over previous
//
#include <hip/hip_runtime.h>
#include <stdint.h>

#define Hdim 112
#define Wdim 112
#define CIN  128
#define COUT 128
#define NB   32
#define HW   (Hdim*Wdim)   // 12544
#define HALO_W 114
#define ROWSTR (HALO_W*16)          // 1824 B per ring row
#define SLOT_STRIDE (4*ROWSTR)      // 7296 B per ci-16 slot (4-row ring)
#define IT 2                        // 2-row slabs per block

// ws layout:
//   Wi8 : int8 [9][COUT][CIN]  @ 0        (147456 B)  weight signs as +-1
//   pkx : uint4[NB*HW]         @ 147456   (6.4 MB)    packed activation sign bits

typedef int   v4i __attribute__((ext_vector_type(4)));
typedef int  v16i __attribute__((ext_vector_type(16)));
typedef float v4f __attribute__((ext_vector_type(4)));

__global__ void pack_w_i8(const float* __restrict__ W, char* __restrict__ Wi8) {
    int t = blockIdx.x * blockDim.x + threadIdx.x;
    if (t >= COUT * 9) return;
    int co = t / 9, tap = t % 9;
    const float* wp = W + (size_t)co * CIN * 9 + tap;
    uint32_t* dst = (uint32_t*)(Wi8 + ((size_t)tap * COUT + co) * CIN);
    #pragma unroll
    for (int c4 = 0; c4 < 32; c4++) {
        uint32_t word = 0;
        #pragma unroll
        for (int j = 0; j < 4; j++) {
            uint32_t neg = __float_as_uint(wp[(size_t)(c4 * 4 + j) * 9]) >> 31;
            word |= (neg ? 0xFFu : 0x01u) << (8 * j);
        }
        dst[c4] = word;
    }
}

// each thread packs 4 consecutive pixels across all 128 channels.
// x is 205 MB single-use -> nontemporal loads keep it out of L2/L3.
__global__ __launch_bounds__(256) void pack_x_kernel(const float* __restrict__ x,
                                                     uint4* __restrict__ pkx) {
    int gid = blockIdx.x * blockDim.x + threadIdx.x;   // 0..100351
    int n = gid / (HW / 4);
    int p = (gid - n * (HW / 4)) * 4;
    const float* xp = x + (size_t)n * CIN * HW + p;
    uint32_t m[4][4] = {{0,0,0,0},{0,0,0,0},{0,0,0,0},{0,0,0,0}};
    #pragma unroll
    for (int c = 0; c < CIN; c++) {
        v4f v = __builtin_nontemporal_load(
            reinterpret_cast<const v4f*>(xp + (size_t)c * HW));
        int q = c >> 5, s = c & 31;
        m[0][q] |= (__float_as_uint(v.x) >> 31) << s;
        m[1][q] |= (__float_as_uint(v.y) >> 31) << s;
        m[2][q] |= (__float_as_uint(v.z) >> 31) << s;
        m[3][q] |= (__float_as_uint(v.w) >> 31) << s;
    }
    uint4* op = pkx + (size_t)n * HW + p;
    #pragma unroll
    for (int j = 0; j < 4; j++)
        op[j] = make_uint4(m[j][0], m[j][1], m[j][2], m[j][3]);
}

// spread low 4 bits into 4 bytes: bit=0 -> 0x01 (+1), bit=1 -> 0xFF (-1)
__device__ __forceinline__ uint32_t expand4(uint32_t b) {
    uint32_t s = ((b & 0xFu) * 0x00204081u) & 0x01010101u;
    return 0x01010101u ^ (s * 0xFEu);
}

// stage one halo pixel (image row h, col w) into ring row `ring`, halo col c
__device__ __forceinline__ void stage_px(const uint4* __restrict__ pkx, char* halo,
                                         int n, int h, int w, int ring, int c) {
    bool valid = (h >= 0) && (h < Hdim) && (w >= 0) && (w < Wdim);
    uint32_t keep = valid ? 0xFFFFFFFFu : 0u;
    int hc = min(max(h, 0), Hdim - 1);
    int wc = min(max(w, 0), Wdim - 1);
    uint4 bits = pkx[(size_t)n * HW + hc * Wdim + wc];
    uint32_t src[4] = {bits.x, bits.y, bits.z, bits.w};
    unsigned base = (unsigned)(ring * ROWSTR + c * 16);
    #pragma unroll
    for (int sl = 0; sl < 8; sl++) {      // slot sl = ci 16sl..16sl+15
        uint32_t q = src[sl >> 1] >> ((sl & 1) * 16);
        uint4 ov;
        ov.x = expand4(q)       & keep;
        ov.y = expand4(q >> 4)  & keep;
        ov.z = expand4(q >> 8)  & keep;
        ov.w = expand4(q >> 12) & keep;
        *reinterpret_cast<uint4*>(&halo[sl * SLOT_STRIDE + base]) = ov;
    }
}

// implicit-GEMM binconv via i8 MFMA — R14 structure + ROLLING 2-SLAB RING.
// R21 verdict: with prefetch provably pinned (FETCH 8.6MB) the 64-col
// reuse_B=2 family is still 1.7x slower than R14 -> R14's full-width
// geometry is the winner; depart from it no further. This round keeps R14
// byte-identical per slab (wave = 32co x 224px, 112-AGPR acc, compiler
// tap-prefetch, NT scalar stores) and only makes each block process TWO
// 2-row slabs with a mod-4 halo row ring:
//   * stage 4 rows once, then +2 rows per slab (halves staging redundancy);
//   * slab0's NT stores stay IN FLIGHT across the restage barriers — raw
//     s_barrier + lgkmcnt(0)-only waits (no __syncthreads vmcnt(0) drain);
//     stores overlap slab1's stage+compute inside the same wave.
// OOB masked after expand -> exact zero padding (absmax 0.0 since R7).
__global__ __launch_bounds__(256, 2) void binconv_mfma(
    const uint4* __restrict__ pkx, const char* __restrict__ Wi8,
    const float* __restrict__ bias, float* __restrict__ out) {
    __shared__ char halo[8 * SLOT_STRIDE];   // 58368 B

    int tid = threadIdx.x;
    int hy = blockIdx.x;                     // 0..27 (4 rows per block)
    int n  = blockIdx.y;
    int h0 = hy * (2 * IT);

    // initial stage: image rows h0-1 .. h0+2 -> ring rows 0..3
    for (int i = tid; i < 4 * HALO_W; i += 256) {
        int r = i / HALO_W, c = i - r * HALO_W;
        stage_px(pkx, halo, n, h0 - 1 + r, c - 1, r, c);
    }

    int wid = tid >> 6, l = tid & 63;
    int al = l & 31, ah = l >> 5;
    int cobase = wid * 32;                   // wave's 32-co slice

    // per-pt: pixel P = pt*32+al of the 2x112 slab tile
    int colb[7], rsel[7], wcol[7];
    #pragma unroll
    for (int pt = 0; pt < 7; pt++) {
        int P = pt * 32 + al;
        rsel[pt] = (P >= Wdim) ? 1 : 0;
        wcol[pt] = P - rsel[pt] * Wdim;
        colb[pt] = wcol[pt] * 16 + ah * SLOT_STRIDE;
    }

    const char* wA = Wi8 + ((size_t)cobase + al) * CIN + ah * 16;
    float* ob = out + (size_t)n * COUT * HW;

    __syncthreads();

    #pragma unroll
    for (int s = 0; s < IT; s++) {
        const int hs = h0 + 2 * s;

        v16i acc[7];
        #pragma unroll
        for (int pt = 0; pt < 7; pt++)
            #pragma unroll
            for (int i = 0; i < 16; i++) acc[pt][i] = 0;

        v4i A[4];
        #pragma unroll
        for (int kk = 0; kk < 4; kk++)
            A[kk] = *reinterpret_cast<const v4i*>(wA + kk * 32);

        #pragma unroll
        for (int tap = 0; tap < 9; tap++) {
            v4i N[4];
            if (tap < 8) {                   // compiler-scheduled prefetch (R14-proven)
                const char* wt = wA + (size_t)(tap + 1) * COUT * CIN;
                #pragma unroll
                for (int kk = 0; kk < 4; kk++)
                    N[kk] = *reinterpret_cast<const v4i*>(wt + kk * 32);
            }
            const int dy = tap / 3, dx = tap % 3;
            int po[7];
            #pragma unroll
            for (int pt = 0; pt < 7; pt++)
                po[pt] = colb[pt] + (((2 * s + dy + rsel[pt]) & 3) * ROWSTR) + dx * 16;
            #pragma unroll
            for (int kk = 0; kk < 4; kk++) {
                v4i b[7];
                #pragma unroll
                for (int pt = 0; pt < 7; pt++)
                    b[pt] = *reinterpret_cast<const v4i*>(&halo[kk * 2 * SLOT_STRIDE + po[pt]]);
                #pragma unroll
                for (int pt = 0; pt < 7; pt++)
                    acc[pt] = __builtin_amdgcn_mfma_i32_32x32x32_i8(A[kk], b[pt], acc[pt], 0, 0, 0);
            }
            if (tap < 8) {
                #pragma unroll
                for (int kk = 0; kk < 4; kk++) A[kk] = N[kk];
            }
        }

        // epilogue: C col=lane&31 (px), row=(reg&3)+8*(reg>>2)+4*ah (co).
        // NT stores issued, NOT drained — they fly across the restage barriers.
        #pragma unroll
        for (int reg = 0; reg < 16; reg++) {
            int co = cobase + (reg & 3) + ((reg >> 2) << 3) + (ah << 2);
            float bv = bias[co];
            #pragma unroll
            for (int pt = 0; pt < 7; pt++) {
                size_t off = (size_t)co * HW + (size_t)(hs + rsel[pt]) * Wdim + wcol[pt];
                __builtin_nontemporal_store((float)acc[pt][reg] + bv, &ob[off]);
            }
        }

        if (s + 1 < IT) {
            // barrier WITHOUT vmcnt drain: only LDS ops must settle.
            asm volatile("s_waitcnt lgkmcnt(0)" ::: "memory");
            __builtin_amdgcn_s_barrier();
            __builtin_amdgcn_sched_barrier(0);
            // restage 2 new rows (hs+3, hs+4) into the 2 oldest ring rows
            for (int i = tid; i < 2 * HALO_W; i += 256) {
                int r = i / HALO_W, c = i - r * HALO_W;
                stage_px(pkx, halo, n, hs + 3 + r, c - 1, (2 * s + r) & 3, c);
            }
            asm volatile("s_waitcnt lgkmcnt(0)" ::: "memory");
            __builtin_amdgcn_s_barrier();
            __builtin_amdgcn_sched_barrier(0);
        }
    }
}

extern "C" void kernel_launch(void* const* d_in, const int* in_sizes, int n_in,
                              void* d_out, int out_size, void* d_ws, size_t ws_size,
                              hipStream_t stream) {
    const float* x = (const float*)d_in[0];
    const float* W = (const float*)d_in[1];
    const float* b = (const float*)d_in[2];
    float* out = (float*)d_out;
    char* ws = (char*)d_ws;
    char*  Wi8 = ws;
    uint4* pkx = (uint4*)(ws + 147456);

    pack_w_i8<<<dim3((COUT * 9 + 255) / 256), dim3(256), 0, stream>>>(W, Wi8);
    pack_x_kernel<<<dim3(NB * HW / 4 / 256), dim3(256), 0, stream>>>(x, pkx);
    binconv_mfma<<<dim3(Hdim / (2 * IT), NB), dim3(256), 0, stream>>>(pkx, Wi8, b, out);
}